// Round 1
// baseline (340.475 us; speedup 1.0000x reference)
//
#include <hip/hip_runtime.h>
#include <hip/hip_bf16.h>
#include <stdint.h>

#define NWIN 1728
#define SPD  110592   // 48*48*48

typedef __attribute__((ext_vector_type(8)))  short  short8;
typedef __attribute__((ext_vector_type(4)))  short  short4v;
typedef __attribute__((ext_vector_type(4)))  float  f32x4;
typedef __attribute__((ext_vector_type(16))) float  f32x16;

__device__ __forceinline__ short f2bf(float f) {
  uint32_t u = __builtin_bit_cast(uint32_t, f);
  u += 0x7FFFu + ((u >> 16) & 1u);          // RTNE
  return (short)(u >> 16);
}
__device__ __forceinline__ float bfhi2f(uint32_t hi_bits) {
  return __builtin_bit_cast(float, hi_bits);
}

// ---- one-time (per launch) fp32 -> bf16 weight conversion into workspace ----
__global__ void cvt_weights_kernel(const float* __restrict__ wqkv,
                                   const float* __restrict__ wout,
                                   short* __restrict__ wq_bf,
                                   short* __restrict__ wo_bf) {
  int i = blockIdx.x * 256 + threadIdx.x;   // grid = 192*256 = 49152 exactly
  wq_bf[i] = f2bf(wqkv[i]);
  if (i < 128 * 128) wo_bf[i] = f2bf(wout[i]);
}

// ---- fused: x -> qkv -> windowed attention -> out projection ----
__global__ __launch_bounds__(256, 2)
void win_attn_kernel(const float* __restrict__ x,
                     const short* __restrict__ wqkv_bf,
                     const short* __restrict__ wout_bf,
                     const float* __restrict__ bout,
                     float* __restrict__ out) {
  // LDS: 17408 + 8192 + 8192 + 9216 + 18432 = 61440 B  (2 blocks/CU)
  __shared__ __align__(16) short sR[64 * 136];    // xs (bf16), later ao (bf16)
  __shared__ __align__(16) short sq[4][64 * 16];  // per-wave q  [t][hd]
  __shared__ __align__(16) short sk[4][64 * 16];  // per-wave k  [t][hd]
  __shared__ __align__(16) short sv[4][16 * 72];  // per-wave v^T [hd][t]
  __shared__ __align__(16) short sp[4][32 * 72];  // per-wave scores/P chunk [row][s]

  const int tid  = threadIdx.x;
  const int lane = tid & 63;
  const int w    = tid >> 6;
  const int blk  = blockIdx.x;
  const int b    = blk / NWIN;
  const int win  = blk - b * NWIN;
  const int id   = win / 144;
  const int ihw  = win - id * 144;
  const int ih   = ihw / 12;
  const int iw   = ihw - ih * 12;

  // ---------- stage x window -> xs bf16 ----------
  const float* xb = x + (size_t)b * (128 * SPD) + id * (4 * 2304) + ih * (4 * 48) + iw * 4;
  #pragma unroll
  for (int i = 0; i < 8; ++i) {
    int idx = i * 256 + tid;          // 0..2047 = (c, dz, hy)
    int c   = idx >> 4;
    int dz  = (idx >> 2) & 3;
    int hy  = idx & 3;
    const float4* src = reinterpret_cast<const float4*>(xb + (size_t)c * SPD + dz * 2304 + hy * 48);
    float4 v = *src;
    int t = dz * 16 + hy * 4;         // token = (wd*4+wh)*4+ww
    sR[(t + 0) * 136 + c] = f2bf(v.x);
    sR[(t + 1) * 136 + c] = f2bf(v.y);
    sR[(t + 2) * 136 + c] = f2bf(v.z);
    sR[(t + 3) * 136 + c] = f2bf(v.w);
  }
  __syncthreads();

  const int m16 = lane & 15, q16 = lane >> 4;   // 16x16 MFMA coords
  const int m32 = lane & 31, h32 = lane >> 5;   // 32x32 MFMA coords

  // preload all A-frags of X (held across both heads)
  short8 afrag[4][4];
  #pragma unroll
  for (int mt = 0; mt < 4; ++mt)
    #pragma unroll
    for (int ks = 0; ks < 4; ++ks)
      afrag[mt][ks] = *reinterpret_cast<const short8*>(
          &sR[(mt * 16 + m16) * 136 + ks * 32 + q16 * 8]);

  f32x4 oacc[2][4];
  #pragma unroll
  for (int i = 0; i < 2; ++i)
    #pragma unroll
    for (int j = 0; j < 4; ++j)
      #pragma unroll
      for (int r = 0; r < 4; ++r) oacc[i][j][r] = 0.0f;

  const float scale = 0.08838834764831845f;   // 128^-0.5

  #pragma unroll
  for (int hh = 0; hh < 2; ++hh) {
    const int h = 2 * w + hh;

    // ---------- QKV for head h: e-tiles h (q), 8+h (k), 16+h (v) ----------
    #pragma unroll
    for (int which = 0; which < 3; ++which) {
      const int et = which * 8 + h;
      f32x4 acc[4];
      #pragma unroll
      for (int mt = 0; mt < 4; ++mt)
        #pragma unroll
        for (int r = 0; r < 4; ++r) acc[mt][r] = 0.0f;
      #pragma unroll
      for (int ks = 0; ks < 4; ++ks) {
        short8 bfrag = *reinterpret_cast<const short8*>(
            wqkv_bf + (et * 16 + m16) * 128 + ks * 32 + q16 * 8);
        #pragma unroll
        for (int mt = 0; mt < 4; ++mt)
          acc[mt] = __builtin_amdgcn_mfma_f32_16x16x32_bf16(afrag[mt][ks], bfrag, acc[mt], 0, 0, 0);
      }
      if (which == 0) {
        #pragma unroll
        for (int mt = 0; mt < 4; ++mt)
          #pragma unroll
          for (int r = 0; r < 4; ++r)
            sq[w][(mt * 16 + q16 * 4 + r) * 16 + m16] = f2bf(acc[mt][r]);
      } else if (which == 1) {
        #pragma unroll
        for (int mt = 0; mt < 4; ++mt)
          #pragma unroll
          for (int r = 0; r < 4; ++r)
            sk[w][(mt * 16 + q16 * 4 + r) * 16 + m16] = f2bf(acc[mt][r]);
      } else {
        #pragma unroll
        for (int mt = 0; mt < 4; ++mt) {
          short4v pk;
          pk[0] = f2bf(acc[mt][0]); pk[1] = f2bf(acc[mt][1]);
          pk[2] = f2bf(acc[mt][2]); pk[3] = f2bf(acc[mt][3]);
          *reinterpret_cast<short4v*>(&sv[w][m16 * 72 + mt * 16 + q16 * 4]) = pk;  // v^T[hd][t]
        }
      }
    }
    asm volatile("s_waitcnt lgkmcnt(0)" ::: "memory");

    // ---------- attention for head h (all wave-local) ----------
    short8 kf0 = *reinterpret_cast<const short8*>(&sk[w][(0 * 32 + m32) * 16 + h32 * 8]);
    short8 kf1 = *reinterpret_cast<const short8*>(&sk[w][(1 * 32 + m32) * 16 + h32 * 8]);
    #pragma unroll
    for (int mt2 = 0; mt2 < 2; ++mt2) {
      short8 qf = *reinterpret_cast<const short8*>(&sq[w][(mt2 * 32 + m32) * 16 + h32 * 8]);
      f32x16 z16;
      #pragma unroll
      for (int i = 0; i < 16; ++i) z16[i] = 0.0f;
      f32x16 s0 = __builtin_amdgcn_mfma_f32_32x32x16_bf16(qf, kf0, z16, 0, 0, 0);
      f32x16 s1 = __builtin_amdgcn_mfma_f32_32x32x16_bf16(qf, kf1, z16, 0, 0, 0);
      asm volatile("s_waitcnt lgkmcnt(0)" ::: "memory");  // prev chunk's P reads done (WAR)
      #pragma unroll
      for (int r = 0; r < 16; ++r) {
        int row = (r & 3) + 8 * (r >> 2) + 4 * h32;       // verified 32x32 C/D row map
        sp[w][row * 72 + m32]      = f2bf(s0[r] * scale);
        sp[w][row * 72 + 32 + m32] = f2bf(s1[r] * scale);
      }
      asm volatile("s_waitcnt lgkmcnt(0)" ::: "memory");
      {  // softmax: lane owns (row = lane>>1, half-row part = lane&1)
        int row = lane >> 1, part = lane & 1;
        short* rp = &sp[w][row * 72 + part * 32];
        float vals[32];
        float mx = -3.0e38f;
        #pragma unroll
        for (int i = 0; i < 16; ++i) {
          uint32_t u = *reinterpret_cast<const uint32_t*>(rp + 2 * i);
          float a  = bfhi2f(u << 16);
          float c2 = bfhi2f(u & 0xFFFF0000u);
          vals[2 * i] = a; vals[2 * i + 1] = c2;
          mx = fmaxf(mx, fmaxf(a, c2));
        }
        mx = fmaxf(mx, __shfl_xor(mx, 1));
        float sum = 0.0f;
        #pragma unroll
        for (int i = 0; i < 32; ++i) { vals[i] = __expf(vals[i] - mx); sum += vals[i]; }
        sum += __shfl_xor(sum, 1);
        float inv = 1.0f / sum;
        #pragma unroll
        for (int i = 0; i < 16; ++i) {
          uint32_t lo = (uint16_t)f2bf(vals[2 * i] * inv);
          uint32_t hi = (uint16_t)f2bf(vals[2 * i + 1] * inv);
          *reinterpret_cast<uint32_t*>(rp + 2 * i) = lo | (hi << 16);
        }
      }
      asm volatile("s_waitcnt lgkmcnt(0)" ::: "memory");
      // PV: O[t][hd] += P[t][s] * V[s][hd], K = 64 over 2 ksteps
      #pragma unroll
      for (int sub = 0; sub < 2; ++sub) {
        #pragma unroll
        for (int ks = 0; ks < 2; ++ks) {
          short8 pf = *reinterpret_cast<const short8*>(
              &sp[w][(sub * 16 + m16) * 72 + ks * 32 + q16 * 8]);
          short8 vf = *reinterpret_cast<const short8*>(
              &sv[w][m16 * 72 + ks * 32 + q16 * 8]);
          oacc[hh][mt2 * 2 + sub] =
              __builtin_amdgcn_mfma_f32_16x16x32_bf16(pf, vf, oacc[hh][mt2 * 2 + sub], 0, 0, 0);
        }
      }
      asm volatile("s_waitcnt lgkmcnt(0)" ::: "memory");
    }
  }
  __syncthreads();   // all waves done with xs/p; reuse sR for ao

  // ---------- assemble ao[t][c] bf16 ----------
  #pragma unroll
  for (int hh = 0; hh < 2; ++hh) {
    int c0 = (2 * w + hh) * 16;
    #pragma unroll
    for (int mt = 0; mt < 4; ++mt)
      #pragma unroll
      for (int r = 0; r < 4; ++r)
        sR[(mt * 16 + q16 * 4 + r) * 136 + c0 + m16] = f2bf(oacc[hh][mt][r]);
  }
  __syncthreads();

  // ---------- out projection: OUT[t][co] = ao[t][:] . Wout[co][:] + bout ----------
  f32x4 outacc[4][2];
  #pragma unroll
  for (int i = 0; i < 4; ++i)
    #pragma unroll
    for (int j = 0; j < 2; ++j)
      #pragma unroll
      for (int r = 0; r < 4; ++r) outacc[i][j][r] = 0.0f;
  #pragma unroll
  for (int ks = 0; ks < 4; ++ks) {
    short8 af[4];
    #pragma unroll
    for (int mt = 0; mt < 4; ++mt)
      af[mt] = *reinterpret_cast<const short8*>(&sR[(mt * 16 + m16) * 136 + ks * 32 + q16 * 8]);
    #pragma unroll
    for (int ntl = 0; ntl < 2; ++ntl) {
      int nt = 2 * w + ntl;
      short8 bfrag = *reinterpret_cast<const short8*>(
          wout_bf + (nt * 16 + m16) * 128 + ks * 32 + q16 * 8);
      #pragma unroll
      for (int mt = 0; mt < 4; ++mt)
        outacc[mt][ntl] = __builtin_amdgcn_mfma_f32_16x16x32_bf16(af[mt], bfrag, outacc[mt][ntl], 0, 0, 0);
    }
  }
  // epilogue: bias + coalesced float4 stores (window-order reshape => contiguous)
  #pragma unroll
  for (int ntl = 0; ntl < 2; ++ntl) {
    int co = (2 * w + ntl) * 16 + m16;
    float bias = bout[co];
    float* obase = out + (size_t)(b * 128 + co) * SPD + win * 64;
    #pragma unroll
    for (int mt = 0; mt < 4; ++mt) {
      float4 vres;
      vres.x = outacc[mt][ntl][0] + bias;
      vres.y = outacc[mt][ntl][1] + bias;
      vres.z = outacc[mt][ntl][2] + bias;
      vres.w = outacc[mt][ntl][3] + bias;
      *reinterpret_cast<float4*>(obase + mt * 16 + q16 * 4) = vres;
    }
  }
}

extern "C" void kernel_launch(void* const* d_in, const int* in_sizes, int n_in,
                              void* d_out, int out_size, void* d_ws, size_t ws_size,
                              hipStream_t stream) {
  const float* x    = (const float*)d_in[0];
  const float* wqkv = (const float*)d_in[1];
  const float* wout = (const float*)d_in[2];
  const float* bout = (const float*)d_in[3];
  short* wq_bf = (short*)d_ws;                       //  98304 B
  short* wo_bf = (short*)((char*)d_ws + 98304);      //  32768 B
  cvt_weights_kernel<<<192, 256, 0, stream>>>(wqkv, wout, wq_bf, wo_bf);
  win_attn_kernel<<<2 * NWIN, 256, 0, stream>>>(x, wq_bf, wo_bf, bout, (float*)d_out);
}

// Round 2
// 294.201 us; speedup vs baseline: 1.1573x; 1.1573x over previous
//
#include <hip/hip_runtime.h>
#include <hip/hip_bf16.h>
#include <stdint.h>

#define NWIN 1728
#define SPD  110592   // 48*48*48

typedef __attribute__((ext_vector_type(8)))  short  short8;
typedef __attribute__((ext_vector_type(4)))  short  short4v;
typedef __attribute__((ext_vector_type(4)))  float  f32x4;
typedef __attribute__((ext_vector_type(16))) float  f32x16;

__device__ __forceinline__ short f2bf(float f) {
  uint32_t u = __builtin_bit_cast(uint32_t, f);
  u += 0x7FFFu + ((u >> 16) & 1u);          // RTNE
  return (short)(u >> 16);
}
__device__ __forceinline__ float bfhi2f(uint32_t hi_bits) {
  return __builtin_bit_cast(float, hi_bits);
}

// ---- one-time (per launch) fp32 -> bf16 weight conversion into workspace ----
__global__ void cvt_weights_kernel(const float* __restrict__ wqkv,
                                   const float* __restrict__ wout,
                                   short* __restrict__ wq_bf,
                                   short* __restrict__ wo_bf) {
  int i = blockIdx.x * 256 + threadIdx.x;   // grid = 192*256 = 49152 exactly
  wq_bf[i] = f2bf(wqkv[i]);
  if (i < 128 * 128) wo_bf[i] = f2bf(wout[i]);
}

// ---- fused: x -> qkv -> windowed attention -> out projection ----
__global__ __launch_bounds__(256, 3)
void win_attn_kernel(const float* __restrict__ x,
                     const short* __restrict__ wqkv_bf,
                     const short* __restrict__ wout_bf,
                     const float* __restrict__ bout,
                     float* __restrict__ out) {
  // LDS: union(sR 17408, sp 18432) + sq 8192 + sk 8192 + sv 9216 = 44032 B
  //   -> 3 blocks/CU (vs 61440 B / 2 blocks before)
  __shared__ __align__(16) short sU[4 * 32 * 72];   // 18432 B: xs / scores / ao
  __shared__ __align__(16) short sq[4][64 * 16];    // per-wave q  [t][hd]
  __shared__ __align__(16) short sk[4][64 * 16];    // per-wave k  [t][hd]
  __shared__ __align__(16) short sv[4][16 * 72];    // per-wave v^T [hd][t]

  short* sR = sU;                                   // xs/ao: [64][136] bf16

  const int tid  = threadIdx.x;
  const int lane = tid & 63;
  const int w    = tid >> 6;

  // XCD swizzle: blockIdx%8 selects the XCD (round-robin dispatch); give each
  // XCD a CONTIGUOUS 432-window chunk so iw-adjacent windows (which share
  // 64-B x cache lines) hit the same per-XCD L2.
  const int blk  = blockIdx.x;                      // 3456 = 8 * 432
  const int g    = (blk & 7) * 432 + (blk >> 3);
  const int b    = g / NWIN;
  const int win  = g - b * NWIN;
  const int id   = win / 144;
  const int ihw  = win - id * 144;
  const int ih   = ihw / 12;
  const int iw   = ihw - ih * 12;

  // ---------- stage x window -> xs bf16 (conflict-free packed writes) ----------
  // work item = (row 0..15, channel-pair 0..63); per wave: fixed row, cp = lane
  // -> ds_write_b32 banks = lane%32 (2 lanes/bank = free)
  const float* xb = x + (size_t)b * (128 * SPD) + id * (4 * 2304) + ih * (4 * 48) + iw * 4;
  uint32_t* sRw = reinterpret_cast<uint32_t*>(sR);
  #pragma unroll
  for (int i = 0; i < 4; ++i) {
    int row = i * 4 + w;              // 0..15 = (dz, hy)
    int cp  = lane;                   // channel pair
    const float* base = xb + (size_t)(cp * 2) * SPD + (row >> 2) * 2304 + (row & 3) * 48;
    float4 v0 = *reinterpret_cast<const float4*>(base);
    float4 v1 = *reinterpret_cast<const float4*>(base + SPD);
    int t = (row >> 2) * 16 + (row & 3) * 4;   // token = (wd*4+wh)*4+ww
    sRw[(t + 0) * 68 + cp] = (uint32_t)(uint16_t)f2bf(v0.x) | ((uint32_t)(uint16_t)f2bf(v1.x) << 16);
    sRw[(t + 1) * 68 + cp] = (uint32_t)(uint16_t)f2bf(v0.y) | ((uint32_t)(uint16_t)f2bf(v1.y) << 16);
    sRw[(t + 2) * 68 + cp] = (uint32_t)(uint16_t)f2bf(v0.z) | ((uint32_t)(uint16_t)f2bf(v1.z) << 16);
    sRw[(t + 3) * 68 + cp] = (uint32_t)(uint16_t)f2bf(v0.w) | ((uint32_t)(uint16_t)f2bf(v1.w) << 16);
  }
  __syncthreads();

  const int m16 = lane & 15, q16 = lane >> 4;   // 16x16 MFMA coords
  const int m32 = lane & 31, h32 = lane >> 5;   // 32x32 MFMA coords

  // preload all A-frags of X into registers (held across both heads)
  short8 afrag[4][4];
  #pragma unroll
  for (int mt = 0; mt < 4; ++mt)
    #pragma unroll
    for (int ks = 0; ks < 4; ++ks)
      afrag[mt][ks] = *reinterpret_cast<const short8*>(
          &sR[(mt * 16 + m16) * 136 + ks * 32 + q16 * 8]);
  __syncthreads();   // xs region is now free -> sp may overlay it

  f32x4 oacc[2][4];
  #pragma unroll
  for (int i = 0; i < 2; ++i)
    #pragma unroll
    for (int j = 0; j < 4; ++j)
      #pragma unroll
      for (int r = 0; r < 4; ++r) oacc[i][j][r] = 0.0f;

  const float scale = 0.08838834764831845f;   // 128^-0.5
  short* spw = sU + w * (32 * 72);            // per-wave score chunk [32][72]

  #pragma unroll
  for (int hh = 0; hh < 2; ++hh) {
    const int h = 2 * w + hh;

    // ---------- QKV for head h: e-tiles h (q), 8+h (k), 16+h (v) ----------
    #pragma unroll
    for (int which = 0; which < 3; ++which) {
      const int et = which * 8 + h;
      f32x4 acc[4];
      #pragma unroll
      for (int mt = 0; mt < 4; ++mt)
        #pragma unroll
        for (int r = 0; r < 4; ++r) acc[mt][r] = 0.0f;
      #pragma unroll
      for (int ks = 0; ks < 4; ++ks) {
        short8 bfrag = *reinterpret_cast<const short8*>(
            wqkv_bf + (et * 16 + m16) * 128 + ks * 32 + q16 * 8);
        #pragma unroll
        for (int mt = 0; mt < 4; ++mt)
          acc[mt] = __builtin_amdgcn_mfma_f32_16x16x32_bf16(afrag[mt][ks], bfrag, acc[mt], 0, 0, 0);
      }
      if (which == 0) {
        #pragma unroll
        for (int mt = 0; mt < 4; ++mt)
          #pragma unroll
          for (int r = 0; r < 4; ++r)
            sq[w][(mt * 16 + q16 * 4 + r) * 16 + m16] = f2bf(acc[mt][r]);
      } else if (which == 1) {
        #pragma unroll
        for (int mt = 0; mt < 4; ++mt)
          #pragma unroll
          for (int r = 0; r < 4; ++r)
            sk[w][(mt * 16 + q16 * 4 + r) * 16 + m16] = f2bf(acc[mt][r]);
      } else {
        #pragma unroll
        for (int mt = 0; mt < 4; ++mt) {
          short4v pk;
          pk[0] = f2bf(acc[mt][0]); pk[1] = f2bf(acc[mt][1]);
          pk[2] = f2bf(acc[mt][2]); pk[3] = f2bf(acc[mt][3]);
          *reinterpret_cast<short4v*>(&sv[w][m16 * 72 + mt * 16 + q16 * 4]) = pk;  // v^T[hd][t]
        }
      }
    }
    asm volatile("s_waitcnt lgkmcnt(0)" ::: "memory");

    // ---------- attention for head h (all wave-local) ----------
    short8 kf0 = *reinterpret_cast<const short8*>(&sk[w][(0 * 32 + m32) * 16 + h32 * 8]);
    short8 kf1 = *reinterpret_cast<const short8*>(&sk[w][(1 * 32 + m32) * 16 + h32 * 8]);
    #pragma unroll
    for (int mt2 = 0; mt2 < 2; ++mt2) {
      short8 qf = *reinterpret_cast<const short8*>(&sq[w][(mt2 * 32 + m32) * 16 + h32 * 8]);
      f32x16 z16;
      #pragma unroll
      for (int i = 0; i < 16; ++i) z16[i] = 0.0f;
      f32x16 s0 = __builtin_amdgcn_mfma_f32_32x32x16_bf16(qf, kf0, z16, 0, 0, 0);
      f32x16 s1 = __builtin_amdgcn_mfma_f32_32x32x16_bf16(qf, kf1, z16, 0, 0, 0);
      asm volatile("s_waitcnt lgkmcnt(0)" ::: "memory");  // prev chunk's P reads done (WAR)
      #pragma unroll
      for (int r = 0; r < 16; ++r) {
        int row = (r & 3) + 8 * (r >> 2) + 4 * h32;       // verified 32x32 C/D row map
        spw[row * 72 + m32]      = f2bf(s0[r] * scale);
        spw[row * 72 + 32 + m32] = f2bf(s1[r] * scale);
      }
      asm volatile("s_waitcnt lgkmcnt(0)" ::: "memory");
      {  // softmax: lane owns (row = lane>>1, half-row part = lane&1)
        int row = lane >> 1, part = lane & 1;
        short* rp = &spw[row * 72 + part * 32];
        float vals[32];
        float mx = -3.0e38f;
        #pragma unroll
        for (int i = 0; i < 16; ++i) {
          uint32_t u = *reinterpret_cast<const uint32_t*>(rp + 2 * i);
          float a  = bfhi2f(u << 16);
          float c2 = bfhi2f(u & 0xFFFF0000u);
          vals[2 * i] = a; vals[2 * i + 1] = c2;
          mx = fmaxf(mx, fmaxf(a, c2));
        }
        mx = fmaxf(mx, __shfl_xor(mx, 1));
        float sum = 0.0f;
        #pragma unroll
        for (int i = 0; i < 32; ++i) { vals[i] = __expf(vals[i] - mx); sum += vals[i]; }
        sum += __shfl_xor(sum, 1);
        float inv = 1.0f / sum;
        #pragma unroll
        for (int i = 0; i < 16; ++i) {
          uint32_t lo = (uint16_t)f2bf(vals[2 * i] * inv);
          uint32_t hi = (uint16_t)f2bf(vals[2 * i + 1] * inv);
          *reinterpret_cast<uint32_t*>(rp + 2 * i) = lo | (hi << 16);
        }
      }
      asm volatile("s_waitcnt lgkmcnt(0)" ::: "memory");
      // PV: O[t][hd] += P[t][s] * V[s][hd], K = 64 over 2 ksteps
      #pragma unroll
      for (int sub = 0; sub < 2; ++sub) {
        #pragma unroll
        for (int ks = 0; ks < 2; ++ks) {
          short8 pf = *reinterpret_cast<const short8*>(
              &spw[(sub * 16 + m16) * 72 + ks * 32 + q16 * 8]);
          short8 vf = *reinterpret_cast<const short8*>(
              &sv[w][m16 * 72 + ks * 32 + q16 * 8]);
          oacc[hh][mt2 * 2 + sub] =
              __builtin_amdgcn_mfma_f32_16x16x32_bf16(pf, vf, oacc[hh][mt2 * 2 + sub], 0, 0, 0);
        }
      }
      asm volatile("s_waitcnt lgkmcnt(0)" ::: "memory");
    }
  }
  __syncthreads();   // all waves done with score chunks; reuse sR for ao

  // ---------- assemble ao[t][c] bf16 ----------
  #pragma unroll
  for (int hh = 0; hh < 2; ++hh) {
    int c0 = (2 * w + hh) * 16;
    #pragma unroll
    for (int mt = 0; mt < 4; ++mt)
      #pragma unroll
      for (int r = 0; r < 4; ++r)
        sR[(mt * 16 + q16 * 4 + r) * 136 + c0 + m16] = f2bf(oacc[hh][mt][r]);
  }
  __syncthreads();

  // ---------- out projection: OUT[t][co] = ao[t][:] . Wout[co][:] + bout ----------
  f32x4 outacc[4][2];
  #pragma unroll
  for (int i = 0; i < 4; ++i)
    #pragma unroll
    for (int j = 0; j < 2; ++j)
      #pragma unroll
      for (int r = 0; r < 4; ++r) outacc[i][j][r] = 0.0f;
  #pragma unroll
  for (int ks = 0; ks < 4; ++ks) {
    short8 af[4];
    #pragma unroll
    for (int mt = 0; mt < 4; ++mt)
      af[mt] = *reinterpret_cast<const short8*>(&sR[(mt * 16 + m16) * 136 + ks * 32 + q16 * 8]);
    #pragma unroll
    for (int ntl = 0; ntl < 2; ++ntl) {
      int nt = 2 * w + ntl;
      short8 bfrag = *reinterpret_cast<const short8*>(
          wout_bf + (nt * 16 + m16) * 128 + ks * 32 + q16 * 8);
      #pragma unroll
      for (int mt = 0; mt < 4; ++mt)
        outacc[mt][ntl] = __builtin_amdgcn_mfma_f32_16x16x32_bf16(af[mt], bfrag, outacc[mt][ntl], 0, 0, 0);
    }
  }
  // epilogue: bias + coalesced float4 stores (window-order reshape => contiguous)
  #pragma unroll
  for (int ntl = 0; ntl < 2; ++ntl) {
    int co = (2 * w + ntl) * 16 + m16;
    float bias = bout[co];
    float* obase = out + (size_t)(b * 128 + co) * SPD + win * 64;
    #pragma unroll
    for (int mt = 0; mt < 4; ++mt) {
      float4 vres;
      vres.x = outacc[mt][ntl][0] + bias;
      vres.y = outacc[mt][ntl][1] + bias;
      vres.z = outacc[mt][ntl][2] + bias;
      vres.w = outacc[mt][ntl][3] + bias;
      *reinterpret_cast<float4*>(obase + mt * 16 + q16 * 4) = vres;
    }
  }
}

extern "C" void kernel_launch(void* const* d_in, const int* in_sizes, int n_in,
                              void* d_out, int out_size, void* d_ws, size_t ws_size,
                              hipStream_t stream) {
  const float* x    = (const float*)d_in[0];
  const float* wqkv = (const float*)d_in[1];
  const float* wout = (const float*)d_in[2];
  const float* bout = (const float*)d_in[3];
  short* wq_bf = (short*)d_ws;                       //  98304 B
  short* wo_bf = (short*)((char*)d_ws + 98304);      //  32768 B
  cvt_weights_kernel<<<192, 256, 0, stream>>>(wqkv, wout, wq_bf, wo_bf);
  win_attn_kernel<<<2 * NWIN, 256, 0, stream>>>(x, wq_bf, wo_bf, bout, (float*)d_out);
}

// Round 4
// 278.235 us; speedup vs baseline: 1.2237x; 1.0574x over previous
//
#include <hip/hip_runtime.h>
#include <hip/hip_bf16.h>
#include <stdint.h>

#define NWIN 1728
#define SPD  110592   // 48*48*48

typedef __attribute__((ext_vector_type(8)))  short  short8;
typedef __attribute__((ext_vector_type(4)))  short  short4v;
typedef __attribute__((ext_vector_type(4)))  float  f32x4;
typedef __attribute__((ext_vector_type(16))) float  f32x16;

// LDS row strides (in shorts). All multiples of 8 (16-B row alignment for b128).
#define SRS 136   // x / ao tile rows
#define SQS 24    // sq/sk rows: 16-B aligned rows, writes 16 banks 2-way
#define SVS 72    // sv / P~ rows (36 words: score b16 stores hit 32 banks 2-way = free)

// zero-cost compiler reorder fence (no instruction emitted)
#define CFENCE() asm volatile("" ::: "memory")
// hard LDS drain (proven R2 ordering for LDS RAW visibility)
#define LFENCE() asm volatile("s_waitcnt lgkmcnt(0)" ::: "memory")

__device__ __forceinline__ short f2bf(float f) {
  uint32_t u = __builtin_bit_cast(uint32_t, f);
  u += 0x7FFFu + ((u >> 16) & 1u);          // RTNE
  return (short)(u >> 16);
}

// ---- one-time (per launch) fp32 -> bf16 weight conversion into workspace ----
__global__ void cvt_weights_kernel(const float* __restrict__ wqkv,
                                   const float* __restrict__ wout,
                                   short* __restrict__ wq_bf,
                                   short* __restrict__ wo_bf) {
  int i = blockIdx.x * 256 + threadIdx.x;   // grid = 192*256 = 49152 exactly
  wq_bf[i] = f2bf(wqkv[i]);
  if (i < 128 * 128) wo_bf[i] = f2bf(wout[i]);
}

// ---- fused: x -> qkv -> windowed attention -> out projection ----
__global__ __launch_bounds__(256, 3)
void win_attn_kernel(const float* __restrict__ x,
                     const short* __restrict__ wqkv_bf,
                     const short* __restrict__ wout_bf,
                     const float* __restrict__ bout,
                     float* __restrict__ out) {
  // LDS: sU 18432 + sq 12288 + sk 12288 + sv 9216 = 52224 B (3 blocks/CU)
  __shared__ __align__(16) short sU[4 * 32 * SVS];   // xs (17408 used) / P~ / ao
  __shared__ __align__(16) short sq[4][64 * SQS];    // per-wave q  [t][hd]
  __shared__ __align__(16) short sk[4][64 * SQS];    // per-wave k  [t][hd]
  __shared__ __align__(16) short sv[4][16 * SVS];    // per-wave v^T [hd][t]

  const int tid  = threadIdx.x;
  const int lane = tid & 63;
  const int w    = tid >> 6;
  const int m16 = lane & 15, q16 = lane >> 4;   // 16x16 MFMA coords
  const int m32 = lane & 31, h32 = lane >> 5;   // 32x32 MFMA coords

  // XCD swizzle: blockIdx%8 = XCD; contiguous 432-window chunk per XCD for L2 reuse
  const int blk  = blockIdx.x;                      // 3456 = 8 * 432
  const int g    = (blk & 7) * 432 + (blk >> 3);
  const int b    = g / NWIN;
  const int win  = g - b * NWIN;
  const int id   = win / 144;
  const int ihw  = win - id * 144;
  const int ih   = ihw / 12;
  const int iw   = ihw - ih * 12;

  short* sR  = sU;                                  // xs/ao: [64][SRS] bf16
  short* spw = sU + w * (32 * SVS);                 // per-wave P~ chunk [32][SVS]

  // prefetch the first QKV weight tile (hh=0, which=0) -> overlaps x staging
  short8 wpre[4];
  #pragma unroll
  for (int ks = 0; ks < 4; ++ks)
    wpre[ks] = *reinterpret_cast<const short8*>(
        wqkv_bf + ((2 * w) * 16 + m16) * 128 + ks * 32 + q16 * 8);

  // ---------- stage x window -> xs bf16 (2 ch packed per b32, conflict-free) ----------
  const float* xb = x + (size_t)b * (128 * SPD) + id * (4 * 2304) + ih * (4 * 48) + iw * 4;
  uint32_t* sRw = reinterpret_cast<uint32_t*>(sR);
  #pragma unroll
  for (int i = 0; i < 4; ++i) {
    int row = i * 4 + w;              // 0..15 = (dz, hy)
    int cp  = lane;                   // channel pair
    const float* base = xb + (size_t)(cp * 2) * SPD + (row >> 2) * 2304 + (row & 3) * 48;
    float4 v0 = *reinterpret_cast<const float4*>(base);
    float4 v1 = *reinterpret_cast<const float4*>(base + SPD);
    int t = (row >> 2) * 16 + (row & 3) * 4;   // token = (wd*4+wh)*4+ww
    sRw[(t + 0) * (SRS / 2) + cp] = (uint32_t)(uint16_t)f2bf(v0.x) | ((uint32_t)(uint16_t)f2bf(v1.x) << 16);
    sRw[(t + 1) * (SRS / 2) + cp] = (uint32_t)(uint16_t)f2bf(v0.y) | ((uint32_t)(uint16_t)f2bf(v1.y) << 16);
    sRw[(t + 2) * (SRS / 2) + cp] = (uint32_t)(uint16_t)f2bf(v0.z) | ((uint32_t)(uint16_t)f2bf(v1.z) << 16);
    sRw[(t + 3) * (SRS / 2) + cp] = (uint32_t)(uint16_t)f2bf(v0.w) | ((uint32_t)(uint16_t)f2bf(v1.w) << 16);
  }
  __syncthreads();

  // preload all A-frags of X into registers (held across both heads)
  short8 afrag[4][4];
  #pragma unroll
  for (int mt = 0; mt < 4; ++mt)
    #pragma unroll
    for (int ks = 0; ks < 4; ++ks)
      afrag[mt][ks] = *reinterpret_cast<const short8*>(
          &sR[(mt * 16 + m16) * SRS + ks * 32 + q16 * 8]);
  __syncthreads();   // xs region free -> P~ chunks may overlay it

  f32x4 oacc[2][4];  // [hh][tile] PV accumulators
  f32x4 inv [2][4];  // [hh][tile] per-row 1/sum (same C/D row mapping as oacc)
  #pragma unroll
  for (int i = 0; i < 2; ++i)
    #pragma unroll
    for (int j = 0; j < 4; ++j)
      #pragma unroll
      for (int r = 0; r < 4; ++r) oacc[i][j][r] = 0.0f;

  const float scale = 0.08838834764831845f;   // 128^-0.5
  f32x16 z16;
  #pragma unroll
  for (int i = 0; i < 16; ++i) z16[i] = 0.0f;
  f32x4 z4;
  #pragma unroll
  for (int i = 0; i < 4; ++i) z4[i] = 0.0f;
  short8 ones8;                                // bf16 1.0 splat (B operand of rowsum MFMA)
  #pragma unroll
  for (int i = 0; i < 8; ++i) ones8[i] = (short)0x3F80;

  #pragma unroll
  for (int hh = 0; hh < 2; ++hh) {
    const int h = 2 * w + hh;

    // ---------- QKV for head h: e-tiles h (q), 8+h (k), 16+h (v) ----------
    #pragma unroll
    for (int which = 0; which < 3; ++which) {
      const int et = which * 8 + h;
      short8 wb[4];
      #pragma unroll
      for (int ks = 0; ks < 4; ++ks)
        wb[ks] = (hh == 0 && which == 0) ? wpre[ks]
               : *reinterpret_cast<const short8*>(
                     wqkv_bf + (et * 16 + m16) * 128 + ks * 32 + q16 * 8);
      f32x4 acc[4];
      #pragma unroll
      for (int mt = 0; mt < 4; ++mt)
        #pragma unroll
        for (int r = 0; r < 4; ++r) acc[mt][r] = 0.0f;
      #pragma unroll
      for (int ks = 0; ks < 4; ++ks)
        #pragma unroll
        for (int mt = 0; mt < 4; ++mt)
          acc[mt] = __builtin_amdgcn_mfma_f32_16x16x32_bf16(afrag[mt][ks], wb[ks], acc[mt], 0, 0, 0);

      if (which == 0) {
        #pragma unroll
        for (int mt = 0; mt < 4; ++mt)
          #pragma unroll
          for (int r = 0; r < 4; ++r)
            sq[w][(mt * 16 + q16 * 4 + r) * SQS + m16] = f2bf(acc[mt][r]);
      } else if (which == 1) {
        #pragma unroll
        for (int mt = 0; mt < 4; ++mt)
          #pragma unroll
          for (int r = 0; r < 4; ++r)
            sk[w][(mt * 16 + q16 * 4 + r) * SQS + m16] = f2bf(acc[mt][r]);
      } else {
        #pragma unroll
        for (int mt = 0; mt < 4; ++mt) {
          short4v pk;
          pk[0] = f2bf(acc[mt][0]); pk[1] = f2bf(acc[mt][1]);
          pk[2] = f2bf(acc[mt][2]); pk[3] = f2bf(acc[mt][3]);
          *reinterpret_cast<short4v*>(&sv[w][m16 * SVS + mt * 16 + q16 * 4]) = pk;  // v^T[hd][t]
        }
      }
    }
    LFENCE();   // sq/sk/sv writes drained (also orders vs previous hh's P~/V reads)

    // ---------- attention for head h (wave-local) ----------
    short8 kf0 = *reinterpret_cast<const short8*>(&sk[w][(m32) * SQS + h32 * 8]);
    short8 kf1 = *reinterpret_cast<const short8*>(&sk[w][(32 + m32) * SQS + h32 * 8]);
    short8 vf0 = *reinterpret_cast<const short8*>(&sv[w][m16 * SVS + q16 * 8]);
    short8 vf1 = *reinterpret_cast<const short8*>(&sv[w][m16 * SVS + 32 + q16 * 8]);
    #pragma unroll
    for (int mt2 = 0; mt2 < 2; ++mt2) {
      short8 qf = *reinterpret_cast<const short8*>(&sq[w][(mt2 * 32 + m32) * SQS + h32 * 8]);
      f32x16 s0 = __builtin_amdgcn_mfma_f32_32x32x16_bf16(qf, kf0, z16, 0, 0, 0);
      f32x16 s1 = __builtin_amdgcn_mfma_f32_32x32x16_bf16(qf, kf1, z16, 0, 0, 0);
      CFENCE();   // WAR: previous chunk's P~ reads issue before these stores
      // store unnormalized P~ = exp(s*scale); no max subtraction (|s*scale| <~ 3)
      #pragma unroll
      for (int r = 0; r < 16; ++r) {
        int row = (r & 3) + 8 * (r >> 2) + 4 * h32;       // 32x32 C/D row map
        spw[row * SVS + m32]      = f2bf(__expf(s0[r] * scale));
        spw[row * SVS + 32 + m32] = f2bf(__expf(s1[r] * scale));
      }
      LFENCE();   // P~ stores drained before A-frag reads
      // PV: O[t][hd] += P~[t][s] * V[s][hd]; row sums via MFMA with B = ones
      #pragma unroll
      for (int sub = 0; sub < 2; ++sub) {
        short8 pf0 = *reinterpret_cast<const short8*>(&spw[(sub * 16 + m16) * SVS + q16 * 8]);
        short8 pf1 = *reinterpret_cast<const short8*>(&spw[(sub * 16 + m16) * SVS + 32 + q16 * 8]);
        int tile = mt2 * 2 + sub;
        oacc[hh][tile] = __builtin_amdgcn_mfma_f32_16x16x32_bf16(pf0, vf0, oacc[hh][tile], 0, 0, 0);
        oacc[hh][tile] = __builtin_amdgcn_mfma_f32_16x16x32_bf16(pf1, vf1, oacc[hh][tile], 0, 0, 0);
        f32x4 rs = __builtin_amdgcn_mfma_f32_16x16x32_bf16(pf0, ones8, z4, 0, 0, 0);
        rs       = __builtin_amdgcn_mfma_f32_16x16x32_bf16(pf1, ones8, rs, 0, 0, 0);
        #pragma unroll
        for (int r = 0; r < 4; ++r) inv[hh][tile][r] = __builtin_amdgcn_rcpf(rs[r]);
      }
    }
  }

  // hoist out-projection weight frags + bias (overlap the barriers below)
  short8 wob[2][4];
  #pragma unroll
  for (int ntl = 0; ntl < 2; ++ntl)
    #pragma unroll
    for (int ks = 0; ks < 4; ++ks)
      wob[ntl][ks] = *reinterpret_cast<const short8*>(
          wout_bf + ((2 * w + ntl) * 16 + m16) * 128 + ks * 32 + q16 * 8);
  float bias0 = bout[(2 * w) * 16 + m16];
  float bias1 = bout[(2 * w + 1) * 16 + m16];

  __syncthreads();   // all waves done with P~ chunks; reuse sR for ao

  // ---------- assemble ao[t][c] bf16, applying 1/rowsum (register-resident) ----------
  #pragma unroll
  for (int hh = 0; hh < 2; ++hh) {
    int c0 = (2 * w + hh) * 16;
    #pragma unroll
    for (int mt = 0; mt < 4; ++mt)
      #pragma unroll
      for (int r = 0; r < 4; ++r)
        sR[(mt * 16 + q16 * 4 + r) * SRS + c0 + m16] = f2bf(oacc[hh][mt][r] * inv[hh][mt][r]);
  }
  __syncthreads();

  // ---------- out projection: OUT[t][co] = ao[t][:] . Wout[co][:] + bout ----------
  f32x4 outacc[4][2];
  #pragma unroll
  for (int i = 0; i < 4; ++i)
    #pragma unroll
    for (int j = 0; j < 2; ++j)
      #pragma unroll
      for (int r = 0; r < 4; ++r) outacc[i][j][r] = 0.0f;
  #pragma unroll
  for (int ks = 0; ks < 4; ++ks) {
    short8 af[4];
    #pragma unroll
    for (int mt = 0; mt < 4; ++mt)
      af[mt] = *reinterpret_cast<const short8*>(&sR[(mt * 16 + m16) * SRS + ks * 32 + q16 * 8]);
    #pragma unroll
    for (int ntl = 0; ntl < 2; ++ntl)
      #pragma unroll
      for (int mt = 0; mt < 4; ++mt)
        outacc[mt][ntl] = __builtin_amdgcn_mfma_f32_16x16x32_bf16(af[mt], wob[ntl][ks], outacc[mt][ntl], 0, 0, 0);
  }
  // epilogue: bias + coalesced float4 stores (window-order reshape => contiguous)
  #pragma unroll
  for (int ntl = 0; ntl < 2; ++ntl) {
    int co = (2 * w + ntl) * 16 + m16;
    float bias = ntl ? bias1 : bias0;
    float* obase = out + (size_t)(b * 128 + co) * SPD + win * 64;
    #pragma unroll
    for (int mt = 0; mt < 4; ++mt) {
      float4 vres;
      vres.x = outacc[mt][ntl][0] + bias;
      vres.y = outacc[mt][ntl][1] + bias;
      vres.z = outacc[mt][ntl][2] + bias;
      vres.w = outacc[mt][ntl][3] + bias;
      *reinterpret_cast<float4*>(obase + mt * 16 + q16 * 4) = vres;
    }
  }
}

extern "C" void kernel_launch(void* const* d_in, const int* in_sizes, int n_in,
                              void* d_out, int out_size, void* d_ws, size_t ws_size,
                              hipStream_t stream) {
  const float* x    = (const float*)d_in[0];
  const float* wqkv = (const float*)d_in[1];
  const float* wout = (const float*)d_in[2];
  const float* bout = (const float*)d_in[3];
  short* wq_bf = (short*)d_ws;                       //  98304 B
  short* wo_bf = (short*)((char*)d_ws + 98304);      //  32768 B
  cvt_weights_kernel<<<192, 256, 0, stream>>>(wqkv, wout, wq_bf, wo_bf);
  win_attn_kernel<<<2 * NWIN, 256, 0, stream>>>(x, wq_bf, wo_bf, bout, (float*)d_out);
}